// Round 2
// baseline (803.940 us; speedup 1.0000x reference)
//
#include <hip/hip_runtime.h>
#include <cstdint>
#include <cstddef>

#define LOG2E 1.44269504088896340736f
#define LN2   0.69314718055994530942f

// Fast transcendental wrappers -> single gfx950 instructions.
// (The __exp2f/__log2f spellings collide with glibc math.h host decls.)
__device__ __forceinline__ float fast_log2(float x) { return __builtin_amdgcn_logf(x); }   // v_log_f32
__device__ __forceinline__ float fast_exp2(float x) { return __builtin_amdgcn_exp2f(x); }  // v_exp_f32
__device__ __forceinline__ float fast_rcp(float x)  { return __builtin_amdgcn_rcpf(x); }   // v_rcp_f32

// B=4096, D_IN=784, D_Z=128, N_TRIALS=256, T_TEMP=1.0

// ---------------------------------------------------------------------------
// K1: encoder GEMM  du = min(x @ W_enc + b_enc, 5)
// grid 256 (BM=16 rows each), block 256. BN=128 (all cols), BK=16.
// ---------------------------------------------------------------------------
__global__ __launch_bounds__(256) void enc_kernel(const float* __restrict__ x,
                                                  const float* __restrict__ W,
                                                  const float* __restrict__ bias,
                                                  float* __restrict__ du) {
  __shared__ float xs[16][16];    // x tile [rows][k]
  __shared__ float ws[16][128];   // W tile [k][cols]
  const int tid  = threadIdx.x;
  const int row0 = blockIdx.x * 16;
  const int cg   = tid & 31;      // column group: cols cg*4 .. cg*4+3
  const int rg   = tid >> 5;      // row group: rows rg*2, rg*2+1

  float4 a0 = {0.f, 0.f, 0.f, 0.f};
  float4 a1 = {0.f, 0.f, 0.f, 0.f};

  for (int k0 = 0; k0 < 784; k0 += 16) {   // 49 exact steps
    __syncthreads();
    if (tid < 64) {                         // 16x16 x-tile: 64 float4
      int r = tid >> 2, kc = (tid & 3) * 4;
      *(float4*)&xs[r][kc] = *(const float4*)&x[(size_t)(row0 + r) * 784 + k0 + kc];
    }
#pragma unroll
    for (int j = 0; j < 2; j++) {           // 16x128 W-tile: 512 float4
      int i = tid + 256 * j;
      int k = i >> 5, c4 = (i & 31) * 4;
      *(float4*)&ws[k][c4] = *(const float4*)&W[(size_t)(k0 + k) * 128 + c4];
    }
    __syncthreads();
#pragma unroll
    for (int k = 0; k < 16; k++) {
      float x0 = xs[rg * 2][k];             // 2 addrs/wave -> LDS broadcast
      float x1 = xs[rg * 2 + 1][k];
      float4 w = *(const float4*)&ws[k][cg * 4];
      a0.x = fmaf(x0, w.x, a0.x); a0.y = fmaf(x0, w.y, a0.y);
      a0.z = fmaf(x0, w.z, a0.z); a0.w = fmaf(x0, w.w, a0.w);
      a1.x = fmaf(x1, w.x, a1.x); a1.y = fmaf(x1, w.y, a1.y);
      a1.z = fmaf(x1, w.z, a1.z); a1.w = fmaf(x1, w.w, a1.w);
    }
  }

  float4 bb = *(const float4*)&bias[cg * 4];
  float4 r0, r1;
  r0.x = fminf(a0.x + bb.x, 5.f); r0.y = fminf(a0.y + bb.y, 5.f);
  r0.z = fminf(a0.z + bb.z, 5.f); r0.w = fminf(a0.w + bb.w, 5.f);
  r1.x = fminf(a1.x + bb.x, 5.f); r1.y = fminf(a1.y + bb.y, 5.f);
  r1.z = fminf(a1.z + bb.z, 5.f); r1.w = fminf(a1.w + bb.w, 5.f);
  *(float4*)&du[(size_t)(row0 + rg * 2)     * 128 + cg * 4] = r0;
  *(float4*)&du[(size_t)(row0 + rg * 2 + 1) * 128 + cg * 4] = r1;
}

// ---------------------------------------------------------------------------
// K2: exponential race. One thread owns one (b, z-pair) cumsum chain.
//   e      = -log1p(-u) = log2(1-u) * (-ln2)
//   times += e / rate   = log2(1-u) * sinv,   sinv = -ln2/rate (folded)
//   z     += sigmoid(1 - times) = 1/(1 + exp2((times-1)*log2e))
// 262144 threads = 1024 blocks x 256 = 4096 waves (16/CU).
// Wave = one b-row of 128 z: float2 loads -> 512 B/wave, perfectly coalesced.
// ---------------------------------------------------------------------------
__global__ __launch_bounds__(256) void race_kernel(const float* __restrict__ u,
                                                   const float* __restrict__ du,
                                                   const float* __restrict__ prior,
                                                   float* __restrict__ zout) {
  const int g  = blockIdx.x * 256 + threadIdx.x;  // 0..262143
  const int b  = g >> 6;                          // batch row
  const int z0 = (g & 63) * 2;                    // z-pair start

  const float2 d = *(const float2*)&du[(size_t)b * 128 + z0];
  const float2 p = *(const float2*)&prior[z0];
  const float lr0 = fminf(d.x + fminf(p.x, 5.f), 5.f);
  const float lr1 = fminf(d.y + fminf(p.y, 5.f), 5.f);
  const float rate0 = fast_exp2(lr0 * LOG2E) + 1e-6f;   // e^lr
  const float rate1 = fast_exp2(lr1 * LOG2E) + 1e-6f;
  const float sinv0 = -LN2 / rate0;   // precise div, once per thread
  const float sinv1 = -LN2 / rate1;

  float t0 = 0.f, t1 = 0.f, acc0 = 0.f, acc1 = 0.f;
  const float* up = u + (size_t)b * 128 + z0;

#pragma unroll 4
  for (int t = 0; t < 256; t++) {
    float2 uu = *(const float2*)&up[(size_t)t * (4096 * 128)];
    float l0 = fast_log2(1.f - uu.x);
    float l1 = fast_log2(1.f - uu.y);
    t0 = fmaf(l0, sinv0, t0);
    t1 = fmaf(l1, sinv1, t1);
    // sigmoid(1-times): exp overflow -> inf -> rcp -> 0, matches stable ref
    float e0 = fast_exp2(fmaf(t0, LOG2E, -LOG2E));
    float e1 = fast_exp2(fmaf(t1, LOG2E, -LOG2E));
    acc0 += fast_rcp(1.f + e0);
    acc1 += fast_rcp(1.f + e1);
  }
  float2 r; r.x = acc0; r.y = acc1;
  *(float2*)&zout[(size_t)b * 128 + z0] = r;
}

// ---------------------------------------------------------------------------
// K3: decoder  y = sigmoid(z @ W_dec + b_dec).  K=128.
// grid 512 (8 b-rows each), block 256. z tile in LDS (broadcast reads);
// W_dec streamed coalesced, reused across 8 b-rows per block.
// ---------------------------------------------------------------------------
__global__ __launch_bounds__(256) void dec_kernel(const float* __restrict__ z,
                                                  const float* __restrict__ W,
                                                  const float* __restrict__ bias,
                                                  float* __restrict__ y) {
  __shared__ float zs[8 * 128];
  const int tid = threadIdx.x;
  const int b0  = blockIdx.x * 8;
  *(float4*)&zs[tid * 4] = *(const float4*)&z[(size_t)b0 * 128 + tid * 4];
  __syncthreads();

  for (int col = tid; col < 784; col += 256) {
    float bv = bias[col];
    float acc[8];
#pragma unroll
    for (int i = 0; i < 8; i++) acc[i] = bv;
#pragma unroll 4
    for (int k = 0; k < 128; k++) {
      float w = W[(size_t)k * 784 + col];   // coalesced; L2-resident (401 KB)
#pragma unroll
      for (int i = 0; i < 8; i++) acc[i] = fmaf(zs[i * 128 + k], w, acc[i]);
    }
#pragma unroll
    for (int i = 0; i < 8; i++) {
      float ex = fast_exp2(-acc[i] * LOG2E);
      y[(size_t)(b0 + i) * 784 + col] = fast_rcp(1.f + ex);
    }
  }
}

// ---------------------------------------------------------------------------
extern "C" void kernel_launch(void* const* d_in, const int* in_sizes, int n_in,
                              void* d_out, int out_size, void* d_ws, size_t ws_size,
                              hipStream_t stream) {
  const float* x     = (const float*)d_in[0];
  const float* u     = (const float*)d_in[1];
  const float* W_enc = (const float*)d_in[2];
  const float* b_enc = (const float*)d_in[3];
  const float* W_dec = (const float*)d_in[4];
  const float* b_dec = (const float*)d_in[5];
  const float* prior = (const float*)d_in[6];

  float* out = (float*)d_out;
  float* du  = out;                       // [4096,128]
  float* zz  = out + 4096 * 128;          // [4096,128]
  float* y   = out + 2 * 4096 * 128;      // [4096,784]

  enc_kernel <<<256,  256, 0, stream>>>(x, W_enc, b_enc, du);
  race_kernel<<<1024, 256, 0, stream>>>(u, du, prior, zz);
  dec_kernel <<<512,  256, 0, stream>>>(zz, W_dec, b_dec, y);
}

// Round 3
// 789.080 us; speedup vs baseline: 1.0188x; 1.0188x over previous
//
#include <hip/hip_runtime.h>
#include <cstdint>
#include <cstddef>

#define LOG2E 1.44269504088896340736f
#define LN2   0.69314718055994530942f

// Fast transcendental wrappers -> single gfx950 instructions.
// (__exp2f/__log2f spellings collide with glibc math.h host decls.)
__device__ __forceinline__ float fast_log2(float x) { return __builtin_amdgcn_logf(x); }   // v_log_f32
__device__ __forceinline__ float fast_exp2(float x) { return __builtin_amdgcn_exp2f(x); }  // v_exp_f32
__device__ __forceinline__ float fast_rcp(float x)  { return __builtin_amdgcn_rcpf(x); }   // v_rcp_f32

// B=4096, D_IN=784, D_Z=128, N_TRIALS=256, T_TEMP=1.0

// ---------------------------------------------------------------------------
// K1: encoder GEMM  du = min(x @ W_enc + b_enc, 5)   (unchanged from R2)
// ---------------------------------------------------------------------------
__global__ __launch_bounds__(256) void enc_kernel(const float* __restrict__ x,
                                                  const float* __restrict__ W,
                                                  const float* __restrict__ bias,
                                                  float* __restrict__ du) {
  __shared__ float xs[16][16];
  __shared__ float ws[16][128];
  const int tid  = threadIdx.x;
  const int row0 = blockIdx.x * 16;
  const int cg   = tid & 31;
  const int rg   = tid >> 5;

  float4 a0 = {0.f, 0.f, 0.f, 0.f};
  float4 a1 = {0.f, 0.f, 0.f, 0.f};

  for (int k0 = 0; k0 < 784; k0 += 16) {
    __syncthreads();
    if (tid < 64) {
      int r = tid >> 2, kc = (tid & 3) * 4;
      *(float4*)&xs[r][kc] = *(const float4*)&x[(size_t)(row0 + r) * 784 + k0 + kc];
    }
#pragma unroll
    for (int j = 0; j < 2; j++) {
      int i = tid + 256 * j;
      int k = i >> 5, c4 = (i & 31) * 4;
      *(float4*)&ws[k][c4] = *(const float4*)&W[(size_t)(k0 + k) * 128 + c4];
    }
    __syncthreads();
#pragma unroll
    for (int k = 0; k < 16; k++) {
      float x0 = xs[rg * 2][k];
      float x1 = xs[rg * 2 + 1][k];
      float4 w = *(const float4*)&ws[k][cg * 4];
      a0.x = fmaf(x0, w.x, a0.x); a0.y = fmaf(x0, w.y, a0.y);
      a0.z = fmaf(x0, w.z, a0.z); a0.w = fmaf(x0, w.w, a0.w);
      a1.x = fmaf(x1, w.x, a1.x); a1.y = fmaf(x1, w.y, a1.y);
      a1.z = fmaf(x1, w.z, a1.z); a1.w = fmaf(x1, w.w, a1.w);
    }
  }

  float4 bb = *(const float4*)&bias[cg * 4];
  float4 r0, r1;
  r0.x = fminf(a0.x + bb.x, 5.f); r0.y = fminf(a0.y + bb.y, 5.f);
  r0.z = fminf(a0.z + bb.z, 5.f); r0.w = fminf(a0.w + bb.w, 5.f);
  r1.x = fminf(a1.x + bb.x, 5.f); r1.y = fminf(a1.y + bb.y, 5.f);
  r1.z = fminf(a1.z + bb.z, 5.f); r1.w = fminf(a1.w + bb.w, 5.f);
  *(float4*)&du[(size_t)(row0 + rg * 2)     * 128 + cg * 4] = r0;
  *(float4*)&du[(size_t)(row0 + rg * 2 + 1) * 128 + cg * 4] = r1;
}

// ---------------------------------------------------------------------------
// K2: exponential race with monotone early exit.
//   times is a non-decreasing cumsum; once times >= 18, remaining sigmoid
//   terms are <= 256*sigmoid(-17) ~ 1e-5 in z (absmax budget 1.6e-2).
//   Per-lane predication: done lanes issue no memory requests, so fully-done
//   128B lines are never fetched (expected ~50% u-traffic cut).
//   Wave ballot break ends the wave at max-lane exit.
// One thread owns a (b, z-quad): float4 loads, 1 KB/wave/instr, 2 trials
// in flight per iteration (Little's law: ~4 MB in flight across 2048 waves).
// ---------------------------------------------------------------------------
__global__ __launch_bounds__(256) void race_kernel(const float* __restrict__ u,
                                                   const float* __restrict__ du,
                                                   const float* __restrict__ prior,
                                                   float* __restrict__ zout) {
  const int g  = blockIdx.x * 256 + threadIdx.x;  // 0..131071
  const int b  = g >> 5;                          // batch row (32 threads/row)
  const int z4 = (g & 31) * 4;                    // z-quad start

  const float4 d = *(const float4*)&du[(size_t)b * 128 + z4];
  const float4 p = *(const float4*)&prior[z4];

  float sinv[4];
  {
    const float dd[4] = {d.x, d.y, d.z, d.w};
    const float pp[4] = {p.x, p.y, p.z, p.w};
#pragma unroll
    for (int j = 0; j < 4; j++) {
      float lr   = fminf(dd[j] + fminf(pp[j], 5.f), 5.f);
      float rate = fast_exp2(lr * LOG2E) + 1e-6f;   // e^lr
      sinv[j]    = -LN2 / rate;                     // folds ln2 and 1/rate
    }
  }

  float t[4]   = {0.f, 0.f, 0.f, 0.f};
  float acc[4] = {0.f, 0.f, 0.f, 0.f};
  const float* up = u + (size_t)b * 128 + z4;
  const float TMAX = 18.f;

  for (int tt = 0; tt < 256; tt += 2) {
    // monotone: once all 4 chains pass TMAX this lane is done forever
    bool act = fminf(fminf(t[0], t[1]), fminf(t[2], t[3])) < TMAX;
    if (!__any(act)) break;          // wave-uniform exit
    if (act) {
      float4 ua = *(const float4*)&up[(size_t)tt * (4096 * 128)];
      float4 ub = *(const float4*)&up[(size_t)(tt + 1) * (4096 * 128)];
      const float uaj[4] = {ua.x, ua.y, ua.z, ua.w};
      const float ubj[4] = {ub.x, ub.y, ub.z, ub.w};
#pragma unroll
      for (int j = 0; j < 4; j++) {
        float l = fast_log2(1.f - uaj[j]);          // -log1p(-u) = -ln2*log2(1-u)
        t[j] = fmaf(l, sinv[j], t[j]);
        float e = fast_exp2(fmaf(t[j], LOG2E, -LOG2E));
        acc[j] += fast_rcp(1.f + e);                // sigmoid(1 - times)
        l = fast_log2(1.f - ubj[j]);
        t[j] = fmaf(l, sinv[j], t[j]);
        e = fast_exp2(fmaf(t[j], LOG2E, -LOG2E));
        acc[j] += fast_rcp(1.f + e);
      }
    }
  }

  float4 r; r.x = acc[0]; r.y = acc[1]; r.z = acc[2]; r.w = acc[3];
  *(float4*)&zout[(size_t)b * 128 + z4] = r;
}

// ---------------------------------------------------------------------------
// K3: decoder  y = sigmoid(z @ W_dec + b_dec)   (unchanged from R2)
// ---------------------------------------------------------------------------
__global__ __launch_bounds__(256) void dec_kernel(const float* __restrict__ z,
                                                  const float* __restrict__ W,
                                                  const float* __restrict__ bias,
                                                  float* __restrict__ y) {
  __shared__ float zs[8 * 128];
  const int tid = threadIdx.x;
  const int b0  = blockIdx.x * 8;
  *(float4*)&zs[tid * 4] = *(const float4*)&z[(size_t)b0 * 128 + tid * 4];
  __syncthreads();

  for (int col = tid; col < 784; col += 256) {
    float bv = bias[col];
    float acc[8];
#pragma unroll
    for (int i = 0; i < 8; i++) acc[i] = bv;
#pragma unroll 4
    for (int k = 0; k < 128; k++) {
      float w = W[(size_t)k * 784 + col];
#pragma unroll
      for (int i = 0; i < 8; i++) acc[i] = fmaf(zs[i * 128 + k], w, acc[i]);
    }
#pragma unroll
    for (int i = 0; i < 8; i++) {
      float ex = fast_exp2(-acc[i] * LOG2E);
      y[(size_t)(b0 + i) * 784 + col] = fast_rcp(1.f + ex);
    }
  }
}

// ---------------------------------------------------------------------------
extern "C" void kernel_launch(void* const* d_in, const int* in_sizes, int n_in,
                              void* d_out, int out_size, void* d_ws, size_t ws_size,
                              hipStream_t stream) {
  const float* x     = (const float*)d_in[0];
  const float* u     = (const float*)d_in[1];
  const float* W_enc = (const float*)d_in[2];
  const float* b_enc = (const float*)d_in[3];
  const float* W_dec = (const float*)d_in[4];
  const float* b_dec = (const float*)d_in[5];
  const float* prior = (const float*)d_in[6];

  float* out = (float*)d_out;
  float* du  = out;                       // [4096,128]
  float* zz  = out + 4096 * 128;          // [4096,128]
  float* y   = out + 2 * 4096 * 128;      // [4096,784]

  enc_kernel <<<256, 256, 0, stream>>>(x, W_enc, b_enc, du);
  race_kernel<<<512, 256, 0, stream>>>(u, du, prior, zz);
  dec_kernel <<<512, 256, 0, stream>>>(zz, W_dec, b_dec, y);
}